// Round 1
// baseline (84.800 us; speedup 1.0000x reference)
//
#include <hip/hip_runtime.h>

#define NN 131072
#define WW 256

__device__ __forceinline__ float clamp01f(float x) { return fminf(fmaxf(x, 0.0f), 1.0f); }

__device__ __forceinline__ float wave_reduce_sum(float v) {
#pragma unroll
    for (int m = 1; m < 64; m <<= 1) v += __shfl_xor(v, m, 64);
    return v;
}

// ---- kernel 1: cosine-sim content addressing: exp_t[i] = exp(beta * cos(mem[i], key_c))
// one wave per row; per-block partial sum of exp_t
__global__ __launch_bounds__(256) void k_content(const float* __restrict__ mem,
                                                 const float* __restrict__ key,
                                                 const float* __restrict__ beta_p,
                                                 float* __restrict__ exp_t,
                                                 float* __restrict__ p1) {
    const int tid  = threadIdx.x;
    const int lane = tid & 63;
    const int wv   = tid >> 6;
    const int wid  = (blockIdx.x << 2) + wv;   // 8192 waves total
    const float beta = beta_p[0];

    float4 k4 = reinterpret_cast<const float4*>(key)[lane];
    k4.x = clamp01f(k4.x); k4.y = clamp01f(k4.y);
    k4.z = clamp01f(k4.z); k4.w = clamp01f(k4.w);
    float ksq = wave_reduce_sum(k4.x * k4.x + k4.y * k4.y + k4.z * k4.z + k4.w * k4.w);
    const float inv_kn = 1.0f / sqrtf(ksq);

    float local = 0.0f;
    for (int row = wid; row < NN; row += 8192) {
        float4 m = reinterpret_cast<const float4*>(mem)[row * 64 + lane];
        float dot = m.x * k4.x + m.y * k4.y + m.z * k4.z + m.w * k4.w;
        float ssq = m.x * m.x + m.y * m.y + m.z * m.z + m.w * m.w;
        dot = wave_reduce_sum(dot);
        ssq = wave_reduce_sum(ssq);
        if (lane == 0) {
            float t = expf(beta * dot * inv_kn / sqrtf(ssq));
            exp_t[row] = t;
            local += t;
        }
    }
    __shared__ float sb[4];
    if (lane == 0) sb[wv] = local;
    __syncthreads();
    if (tid == 0) p1[blockIdx.x] = (sb[0] + sb[1]) + (sb[2] + sb[3]);
}

// ---- generic single-block reduction: out[0] = sum(in[0..n))
__global__ __launch_bounds__(256) void k_reduce(const float* __restrict__ in, int n,
                                                float* __restrict__ out) {
    __shared__ float red[256];
    const int tid = threadIdx.x;
    float s = 0.0f;
    for (int i = tid; i < n; i += 256) s += in[i];
    red[tid] = s;
    __syncthreads();
    for (int st = 128; st > 0; st >>= 1) {
        if (tid < st) red[tid] += red[tid + st];
        __syncthreads();
    }
    if (tid == 0) out[0] = red[0];
}

// ---- kernel 3: wg = gate*softmax + (1-gate)*clamp01(w_prev)
__global__ __launch_bounds__(256) void k_gate(const float* __restrict__ exp_t,
                                              const float* __restrict__ w_prev,
                                              const float* __restrict__ gate_p,
                                              const float* __restrict__ scal,
                                              float* __restrict__ wg) {
    const int i = blockIdx.x * 256 + threadIdx.x;
    const float g = gate_p[0];
    const float invS1 = 1.0f / scal[0];
    wg[i] = g * (exp_t[i] * invS1) + (1.0f - g) * clamp01f(w_prev[i]);
}

// ---- kernel 4: circular shift + sharpen (pow), per-block partial sums
__global__ __launch_bounds__(256) void k_shift_pow(const float* __restrict__ wg,
                                                   const float* __restrict__ shift,
                                                   const float* __restrict__ gamma_p,
                                                   float* __restrict__ wlp,
                                                   float* __restrict__ p2) {
    const int i = blockIdx.x * 256 + threadIdx.x;
    const float s0 = clamp01f(shift[0]);
    const float s1 = clamp01f(shift[1]);
    const float s2 = clamp01f(shift[2]);
    const float gmm = gamma_p[0];
    const float wl = s0 * wg[(i + 1) & (NN - 1)] + s1 * wg[i] + s2 * wg[(i + NN - 1) & (NN - 1)];
    const float v = powf(wl, gmm);
    wlp[i] = v;
    __shared__ float red[256];
    red[threadIdx.x] = v;
    __syncthreads();
    for (int st = 128; st > 0; st >>= 1) {
        if (threadIdx.x < st) red[threadIdx.x] += red[threadIdx.x + st];
        __syncthreads();
    }
    if (threadIdx.x == 0) p2[blockIdx.x] = red[0];
}

// ---- kernel 6: normalize w, write w out, read mem, write new_mem, accumulate r partials
__global__ __launch_bounds__(256) void k_update(const float* __restrict__ mem,
                                                const float* __restrict__ wlp,
                                                const float* __restrict__ scal,
                                                const float* __restrict__ e,
                                                const float* __restrict__ a,
                                                float* __restrict__ out_mem,
                                                float* __restrict__ out_w,
                                                float* __restrict__ rp) {
    const int tid  = threadIdx.x;
    const int lane = tid & 63;
    const int wv   = tid >> 6;
    const int wid  = (blockIdx.x << 2) + wv;
    const float invS2 = 1.0f / scal[1];

    float4 e4 = reinterpret_cast<const float4*>(e)[lane];
    e4.x = clamp01f(e4.x); e4.y = clamp01f(e4.y);
    e4.z = clamp01f(e4.z); e4.w = clamp01f(e4.w);
    float4 a4 = reinterpret_cast<const float4*>(a)[lane];
    a4.x = clamp01f(a4.x); a4.y = clamp01f(a4.y);
    a4.z = clamp01f(a4.z); a4.w = clamp01f(a4.w);

    float4 racc = make_float4(0.0f, 0.0f, 0.0f, 0.0f);
    for (int row = wid; row < NN; row += 8192) {
        const float wi = wlp[row] * invS2;   // broadcast read
        const float wr = clamp01f(wi);
        if (lane == 0) out_w[row] = wi;
        float4 m = reinterpret_cast<const float4*>(mem)[row * 64 + lane];
        float4 nm;
        nm.x = m.x * (1.0f - wr * e4.x) + wr * a4.x;
        nm.y = m.y * (1.0f - wr * e4.y) + wr * a4.y;
        nm.z = m.z * (1.0f - wr * e4.z) + wr * a4.z;
        nm.w = m.w * (1.0f - wr * e4.w) + wr * a4.w;
        reinterpret_cast<float4*>(out_mem)[row * 64 + lane] = nm;
        racc.x += wr * m.x;
        racc.y += wr * m.y;
        racc.z += wr * m.z;
        racc.w += wr * m.w;
    }
    __shared__ float lds[4 * 256];
    reinterpret_cast<float4*>(lds)[wv * 64 + lane] = racc;
    __syncthreads();
    // column tid: sum 4 wave partials
    const float s = lds[0 * 256 + tid] + lds[1 * 256 + tid] + lds[2 * 256 + tid] + lds[3 * 256 + tid];
    rp[blockIdx.x * 256 + tid] = s;
}

// ---- r reduction stage 1: 32 blocks, block b sums partial rows [b*64, b*64+64)
__global__ __launch_bounds__(256) void k_rstage(const float* __restrict__ rp,
                                                float* __restrict__ rp2) {
    const int tid = threadIdx.x;
    const int b   = blockIdx.x;
    float s = 0.0f;
    for (int k = 0; k < 64; ++k) s += rp[(b * 64 + k) * 256 + tid];
    rp2[b * 256 + tid] = s;
}

// ---- r reduction stage 2: final r[256]
__global__ __launch_bounds__(256) void k_rfinal(const float* __restrict__ rp2,
                                                float* __restrict__ out_r) {
    const int tid = threadIdx.x;
    float s = 0.0f;
    for (int b = 0; b < 32; ++b) s += rp2[b * 256 + tid];
    out_r[tid] = s;
}

extern "C" void kernel_launch(void* const* d_in, const int* in_sizes, int n_in,
                              void* d_out, int out_size, void* d_ws, size_t ws_size,
                              hipStream_t stream) {
    const float* mem    = (const float*)d_in[0];
    const float* key    = (const float*)d_in[1];
    const float* beta_p = (const float*)d_in[2];
    const float* gamma_p= (const float*)d_in[3];
    const float* gate_p = (const float*)d_in[4];
    const float* shift  = (const float*)d_in[5];
    const float* w_prev = (const float*)d_in[6];
    const float* e      = (const float*)d_in[7];
    const float* a      = (const float*)d_in[8];

    float* out   = (float*)d_out;
    float* out_r = out;                       // [256]
    float* out_m = out + WW;                  // [131072*256]
    float* out_w = out + WW + (size_t)NN * WW;// [131072]

    float* ws = (float*)d_ws;
    float* exp_t = ws;                        // N
    float* wg    = ws + NN;                   // N
    float* wlp   = ws + 2 * NN;               // N
    float* p1    = ws + 3 * NN;               // 2048
    float* p2    = p1 + 2048;                 // 512
    float* scal  = p2 + 512;                  // 2
    float* rp    = scal + 64;                 // 2048*256 (padded start)
    float* rp2   = rp + 2048 * 256;           // 32*256

    k_content<<<2048, 256, 0, stream>>>(mem, key, beta_p, exp_t, p1);
    k_reduce<<<1, 256, 0, stream>>>(p1, 2048, &scal[0]);
    k_gate<<<512, 256, 0, stream>>>(exp_t, w_prev, gate_p, scal, wg);
    k_shift_pow<<<512, 256, 0, stream>>>(wg, shift, gamma_p, wlp, p2);
    k_reduce<<<1, 256, 0, stream>>>(p2, 512, &scal[1]);
    k_update<<<2048, 256, 0, stream>>>(mem, wlp, scal, e, a, out_m, out_w, rp);
    k_rstage<<<32, 256, 0, stream>>>(rp, rp2);
    k_rfinal<<<1, 256, 0, stream>>>(rp2, out_r);
}

// Round 3
// 78.762 us; speedup vs baseline: 1.0767x; 1.0767x over previous
//
#include <hip/hip_runtime.h>

#define NN 131072
#define WW 256

typedef float f32x4 __attribute__((ext_vector_type(4)));

__device__ __forceinline__ float clamp01f(float x) { return fminf(fmaxf(x, 0.0f), 1.0f); }

__device__ __forceinline__ float wave_reduce_sum(float v) {
#pragma unroll
    for (int m = 1; m < 64; m <<= 1) v += __shfl_xor(v, m, 64);
    return v;
}

// ---- kernel 1: exp_t[i] = exp(beta * cos(mem[i], key_c)); per-block partial sums -> p1
__global__ __launch_bounds__(256) void k_content(const float* __restrict__ mem,
                                                 const float* __restrict__ key,
                                                 const float* __restrict__ beta_p,
                                                 float* __restrict__ exp_t,
                                                 float* __restrict__ p1) {
    const int tid  = threadIdx.x;
    const int lane = tid & 63;
    const int wv   = tid >> 6;
    const int wid  = (blockIdx.x << 2) + wv;   // 8192 waves total
    const float beta = beta_p[0];

    float4 k4 = reinterpret_cast<const float4*>(key)[lane];
    k4.x = clamp01f(k4.x); k4.y = clamp01f(k4.y);
    k4.z = clamp01f(k4.z); k4.w = clamp01f(k4.w);
    float ksq = wave_reduce_sum(k4.x * k4.x + k4.y * k4.y + k4.z * k4.z + k4.w * k4.w);
    const float inv_kn = 1.0f / sqrtf(ksq);

    float local = 0.0f;
    for (int row = wid; row < NN; row += 8192) {
        float4 m = reinterpret_cast<const float4*>(mem)[row * 64 + lane];
        float dot = m.x * k4.x + m.y * k4.y + m.z * k4.z + m.w * k4.w;
        float ssq = m.x * m.x + m.y * m.y + m.z * m.z + m.w * m.w;
        dot = wave_reduce_sum(dot);
        ssq = wave_reduce_sum(ssq);
        if (lane == 0) {
            float t = expf(beta * dot * inv_kn / sqrtf(ssq));
            exp_t[row] = t;
            local += t;
        }
    }
    __shared__ float sb[4];
    if (lane == 0) sb[wv] = local;
    __syncthreads();
    if (tid == 0) p1[blockIdx.x] = (sb[0] + sb[1]) + (sb[2] + sb[3]);
}

// ---- kernel 2 (fused): S1 = sum(p1); wg on-the-fly; circular shift; pow; partials -> p2
__global__ __launch_bounds__(256) void k_shift_pow(const float* __restrict__ exp_t,
                                                   const float* __restrict__ w_prev,
                                                   const float* __restrict__ p1,
                                                   const float* __restrict__ gate_p,
                                                   const float* __restrict__ shift,
                                                   const float* __restrict__ gamma_p,
                                                   float* __restrict__ wlp,
                                                   float* __restrict__ p2) {
    __shared__ float red[256];
    const int tid = threadIdx.x;
    // S1 reduction (every block, 8 KB L2-hit)
    float s = 0.0f;
#pragma unroll
    for (int k = 0; k < 8; ++k) s += p1[tid + 256 * k];
    red[tid] = s;
    __syncthreads();
    for (int st = 128; st > 0; st >>= 1) {
        if (tid < st) red[tid] += red[tid + st];
        __syncthreads();
    }
    const float invS1 = 1.0f / red[0];
    __syncthreads();

    const float g  = gate_p[0];
    const float s0 = clamp01f(shift[0]);
    const float s1 = clamp01f(shift[1]);
    const float s2 = clamp01f(shift[2]);
    const float gmm = gamma_p[0];
    const int i = blockIdx.x * 256 + tid;

    const int ip = (i + 1) & (NN - 1);
    const int im = (i + NN - 1) & (NN - 1);
    const float wg_p = g * (exp_t[ip] * invS1) + (1.0f - g) * clamp01f(w_prev[ip]);
    const float wg_c = g * (exp_t[i]  * invS1) + (1.0f - g) * clamp01f(w_prev[i]);
    const float wg_m = g * (exp_t[im] * invS1) + (1.0f - g) * clamp01f(w_prev[im]);
    const float wl = s0 * wg_p + s1 * wg_c + s2 * wg_m;
    const float v  = powf(wl, gmm);
    wlp[i] = v;

    red[tid] = v;
    __syncthreads();
    for (int st = 128; st > 0; st >>= 1) {
        if (tid < st) red[tid] += red[tid + st];
        __syncthreads();
    }
    if (tid == 0) p2[blockIdx.x] = red[0];
}

// ---- kernel 3 (fused): S2 = sum(p2); normalize w; write w; erase+add; r partials
__global__ __launch_bounds__(256) void k_update(const float* __restrict__ mem,
                                                const float* __restrict__ wlp,
                                                const float* __restrict__ p2,
                                                const float* __restrict__ e,
                                                const float* __restrict__ a,
                                                float* __restrict__ out_mem,
                                                float* __restrict__ out_w,
                                                float* __restrict__ rp) {
    __shared__ float lds[4 * 256];
    const int tid  = threadIdx.x;
    const int lane = tid & 63;
    const int wv   = tid >> 6;
    const int wid  = (blockIdx.x << 2) + wv;

    // S2 reduction (every block, 2 KB L2-hit)
    lds[tid] = p2[tid] + p2[tid + 256];
    __syncthreads();
    for (int st = 128; st > 0; st >>= 1) {
        if (tid < st) lds[tid] += lds[tid + st];
        __syncthreads();
    }
    const float invS2 = 1.0f / lds[0];
    __syncthreads();

    float4 e4 = reinterpret_cast<const float4*>(e)[lane];
    e4.x = clamp01f(e4.x); e4.y = clamp01f(e4.y);
    e4.z = clamp01f(e4.z); e4.w = clamp01f(e4.w);
    float4 a4 = reinterpret_cast<const float4*>(a)[lane];
    a4.x = clamp01f(a4.x); a4.y = clamp01f(a4.y);
    a4.z = clamp01f(a4.z); a4.w = clamp01f(a4.w);

    float4 racc = make_float4(0.0f, 0.0f, 0.0f, 0.0f);
    for (int row = wid; row < NN; row += 8192) {
        const float wi = wlp[row] * invS2;   // broadcast read
        const float wr = clamp01f(wi);
        if (lane == 0) out_w[row] = wi;
        float4 m = reinterpret_cast<const float4*>(mem)[row * 64 + lane];
        f32x4 nm;
        nm.x = m.x * (1.0f - wr * e4.x) + wr * a4.x;
        nm.y = m.y * (1.0f - wr * e4.y) + wr * a4.y;
        nm.z = m.z * (1.0f - wr * e4.z) + wr * a4.z;
        nm.w = m.w * (1.0f - wr * e4.w) + wr * a4.w;
        __builtin_nontemporal_store(nm, reinterpret_cast<f32x4*>(out_mem) + row * 64 + lane);
        racc.x += wr * m.x;
        racc.y += wr * m.y;
        racc.z += wr * m.z;
        racc.w += wr * m.w;
    }
    reinterpret_cast<float4*>(lds)[wv * 64 + lane] = racc;
    __syncthreads();
    const float s = lds[0 * 256 + tid] + lds[1 * 256 + tid] + lds[2 * 256 + tid] + lds[3 * 256 + tid];
    rp[blockIdx.x * 256 + tid] = s;
}

// ---- r reduction stage 1: 32 blocks, block b sums partial rows [b*64, b*64+64)
__global__ __launch_bounds__(256) void k_rstage(const float* __restrict__ rp,
                                                float* __restrict__ rp2) {
    const int tid = threadIdx.x;
    const int b   = blockIdx.x;
    float s = 0.0f;
    for (int k = 0; k < 64; ++k) s += rp[(b * 64 + k) * 256 + tid];
    rp2[b * 256 + tid] = s;
}

// ---- r reduction stage 2: final r[256]
__global__ __launch_bounds__(256) void k_rfinal(const float* __restrict__ rp2,
                                                float* __restrict__ out_r) {
    const int tid = threadIdx.x;
    float s = 0.0f;
    for (int b = 0; b < 32; ++b) s += rp2[b * 256 + tid];
    out_r[tid] = s;
}

extern "C" void kernel_launch(void* const* d_in, const int* in_sizes, int n_in,
                              void* d_out, int out_size, void* d_ws, size_t ws_size,
                              hipStream_t stream) {
    const float* mem    = (const float*)d_in[0];
    const float* key    = (const float*)d_in[1];
    const float* beta_p = (const float*)d_in[2];
    const float* gamma_p= (const float*)d_in[3];
    const float* gate_p = (const float*)d_in[4];
    const float* shift  = (const float*)d_in[5];
    const float* w_prev = (const float*)d_in[6];
    const float* e      = (const float*)d_in[7];
    const float* a      = (const float*)d_in[8];

    float* out   = (float*)d_out;
    float* out_r = out;                        // [256]
    float* out_m = out + WW;                   // [131072*256]
    float* out_w = out + WW + (size_t)NN * WW; // [131072]

    float* ws = (float*)d_ws;
    float* exp_t = ws;                         // N
    float* wlp   = ws + NN;                    // N
    float* p1    = ws + 2 * NN;                // 2048
    float* p2    = p1 + 2048;                  // 512
    float* rp    = p2 + 512;                   // 2048*256
    float* rp2   = rp + 2048 * 256;            // 32*256

    k_content<<<2048, 256, 0, stream>>>(mem, key, beta_p, exp_t, p1);
    k_shift_pow<<<512, 256, 0, stream>>>(exp_t, w_prev, p1, gate_p, shift, gamma_p, wlp, p2);
    k_update<<<2048, 256, 0, stream>>>(mem, wlp, p2, e, a, out_m, out_w, rp);
    k_rstage<<<32, 256, 0, stream>>>(rp, rp2);
    k_rfinal<<<1, 256, 0, stream>>>(rp2, out_r);
}